// Round 4
// baseline (283.102 us; speedup 1.0000x reference)
//
#include <hip/hip_runtime.h>
#include <hip/hip_fp16.h>
#include <cstdint>
#include <cstddef>

// OccupancyModel: feats = grid[round(clip(p*127))]  (2M x 16 gather)
//   h1 = relu(feats @ W1^T + b1)   (16 -> 64)
//   h2 = relu(h1 @ W2^T + b2)      (64 -> 64)
//   occ = tanh(h2 @ W3^T + b3)     (64 -> 1)
//
// fp16 MFMA (mfma_f32_16x16x32_f16, fp32 acc), H^T = W @ feats^T: points on
// the MFMA n-dim (col = lane&15); layer1->layer2 relayout = cross-quad
// shuffles, no LDS, no barriers.
//
// R4: R2/R3 batching was structurally impossible: without an explicit
// min-waves bound the allocator targeted ~72 VGPRs (< the 80 loop-invariant
// weight regs), forcing weight remat + gather sinking -> serial chain,
// latency-bound at ~118us with every pipe idle. This round:
//   * __launch_bounds__(256, 2): VGPR cap 256 -> weights + batch may live.
//   * asm volatile("" ::: "memory") fence after the gather phase: no pass
//     may sink a load across a may-write asm (sched_barrier couldn't stop
//     MachineSink; this does).
//   * 8 tiles (128 points) per batch: 16 gather dwordx4 + 24 pts dwords in
//     flight per wave -> latency paid once per ~2000 cyc of MLP.

typedef _Float16 half8 __attribute__((ext_vector_type(8)));
typedef float float4v __attribute__((ext_vector_type(4)));

#define NT 8  // tiles per batch

__device__ inline uint32_t pack_f16x2(float a, float b) {
    union { _Float16 h[2]; uint32_t u; } v;
    v.h[0] = (_Float16)a;
    v.h[1] = (_Float16)b;
    return v.u;
}

__global__ __launch_bounds__(256, 2) void occ_mlp_kernel(
    const float* __restrict__ pts,
    const float* __restrict__ grid,
    const float* __restrict__ W1, const float* __restrict__ b1,
    const float* __restrict__ W2, const float* __restrict__ b2,
    const float* __restrict__ W3, const float* __restrict__ b3,
    float* __restrict__ out, int nPoints)
{
    const int lane = threadIdx.x & 63;
    const int l15  = lane & 15;
    const int quad = lane >> 4;
    const int wavesPerBlock = blockDim.x >> 6;
    const int waveId = blockIdx.x * wavesPerBlock + (threadIdx.x >> 6);
    const int nWaves = gridDim.x * wavesPerBlock;

    // ---- loop-invariant weight fragments (80 VGPRs, now allowed to live) ----
    // A layout: A[m = lane&15][k = quad*8 + j].  Layer1 K=16 padded to 32;
    // b1 folded at k=16 (quad2 j=0), bfrag's k=16 slot = 1.0.
    half8 A1[4];
#pragma unroll
    for (int t = 0; t < 4; ++t) {
        half8 f = {};
        if (quad < 2) {
            const float* row = W1 + (16 * t + l15) * 16 + quad * 8;
#pragma unroll
            for (int j = 0; j < 8; ++j) f[j] = (_Float16)row[j];
        } else if (quad == 2) {
            f[0] = (_Float16)b1[16 * t + l15];
        }
        A1[t] = f;
    }
    half8 A2[4][2];
#pragma unroll
    for (int t = 0; t < 4; ++t)
#pragma unroll
        for (int kk = 0; kk < 2; ++kk) {
            const float* row = W2 + (16 * t + l15) * 64 + 32 * kk + 8 * quad;
            half8 f;
#pragma unroll
            for (int j = 0; j < 8; ++j) f[j] = (_Float16)row[j];
            A2[t][kk] = f;
        }
    // C/D layout: col = lane&15 (point), row = quad*4 + reg.
    float4v bias2[4];
    float w3v[4][4];
#pragma unroll
    for (int t = 0; t < 4; ++t)
#pragma unroll
        for (int r = 0; r < 4; ++r) {
            int h = 16 * t + 4 * quad + r;
            bias2[t][r] = b2[h];
            w3v[t][r]   = W3[h];
        }
    const float bias3 = b3[0];

    // layer1->layer2 cross-quad shuffle plan
    const int src0 = l15 + 16 * ((2 * quad) & 3);
    const int src1 = l15 + 16 * ((2 * quad + 1) & 3);
    const bool sel = (quad >> 1) != 0;

    const int nTiles = (nPoints + 15) >> 4;
    for (int tb = waveId * NT; tb < nTiles; tb += nWaves * NT) {

        // ---- phase A: NT tiles' point loads + index math ----
        int ofs[NT];
#pragma unroll
        for (int u = 0; u < NT; ++u) {
            int p = (tb + u) * 16 + l15;
            int pc = p < nPoints ? p : nPoints - 1;
            const float px = pts[3 * pc + 0];
            const float py = pts[3 * pc + 1];
            const float pz = pts[3 * pc + 2];
            const int ix = (int)rintf(fminf(fmaxf(px * 127.0f, 0.0f), 127.0f));
            const int iy = (int)rintf(fminf(fmaxf(py * 127.0f, 0.0f), 127.0f));
            const int iz = (int)rintf(fminf(fmaxf(pz * 127.0f, 0.0f), 127.0f));
            ofs[u] = ((((ix << 7) | iy) << 7) | iz) << 4;
        }

        // ---- phase B: all 2*NT gather dwordx4s issued before ANY compute ----
        float4 g0[NT] = {}, g1[NT] = {};
#pragma unroll
        for (int u = 0; u < NT; ++u) {
            if (quad < 2) {
                const float4* gp = reinterpret_cast<const float4*>(grid + ofs[u] + quad * 8);
                g0[u] = gp[0];
                g1[u] = gp[1];
            }
        }
        // Compiler-level full memory fence: NO pass may move a load across a
        // may-write asm. The 16 dwordx4s above stay issued here; results must
        // live in VGPRs across it.
        asm volatile("" ::: "memory");

        // ---- phase C: per-tile MLP ----
        float o[NT];
#pragma unroll
        for (int u = 0; u < NT; ++u) {
            half8 bfrag = {};
            if (quad < 2) {
                bfrag[0] = (_Float16)g0[u].x; bfrag[1] = (_Float16)g0[u].y;
                bfrag[2] = (_Float16)g0[u].z; bfrag[3] = (_Float16)g0[u].w;
                bfrag[4] = (_Float16)g1[u].x; bfrag[5] = (_Float16)g1[u].y;
                bfrag[6] = (_Float16)g1[u].z; bfrag[7] = (_Float16)g1[u].w;
            } else if (quad == 2) {
                bfrag[0] = (_Float16)1.0f;  // multiplies the folded b1 column
            }

            // layer 1 (bias via folded K-slot)
            float4v C1[4];
#pragma unroll
            for (int t = 0; t < 4; ++t) {
                float4v z = {};
                C1[t] = __builtin_amdgcn_mfma_f32_16x16x32_f16(A1[t], bfrag, z, 0, 0, 0);
            }

            // relu + fp16 pack
            uint32_t P[4][2];
#pragma unroll
            for (int t = 0; t < 4; ++t) {
                const float v0 = fmaxf(C1[t][0], 0.0f);
                const float v1 = fmaxf(C1[t][1], 0.0f);
                const float v2 = fmaxf(C1[t][2], 0.0f);
                const float v3 = fmaxf(C1[t][3], 0.0f);
                P[t][0] = pack_f16x2(v0, v1);
                P[t][1] = pack_f16x2(v2, v3);
            }

            // cross-quad shuffle into layer-2 B fragments
            union Frag { uint32_t u[4]; half8 h; } B2[2];
#pragma unroll
            for (int kk = 0; kk < 2; ++kk) {
                const uint32_t x0a = (uint32_t)__shfl((int)P[2 * kk    ][0], src0);
                const uint32_t x0b = (uint32_t)__shfl((int)P[2 * kk + 1][0], src0);
                const uint32_t x1a = (uint32_t)__shfl((int)P[2 * kk    ][1], src0);
                const uint32_t x1b = (uint32_t)__shfl((int)P[2 * kk + 1][1], src0);
                const uint32_t y0a = (uint32_t)__shfl((int)P[2 * kk    ][0], src1);
                const uint32_t y0b = (uint32_t)__shfl((int)P[2 * kk + 1][0], src1);
                const uint32_t y1a = (uint32_t)__shfl((int)P[2 * kk    ][1], src1);
                const uint32_t y1b = (uint32_t)__shfl((int)P[2 * kk + 1][1], src1);
                B2[kk].u[0] = sel ? x0b : x0a;
                B2[kk].u[1] = sel ? x1b : x1a;
                B2[kk].u[2] = sel ? y0b : y0a;
                B2[kk].u[3] = sel ? y1b : y1a;
            }

            // layer 2
            float4v C2[4];
#pragma unroll
            for (int t = 0; t < 4; ++t) C2[t] = bias2[t];
#pragma unroll
            for (int kk = 0; kk < 2; ++kk)
#pragma unroll
                for (int t = 0; t < 4; ++t)
                    C2[t] = __builtin_amdgcn_mfma_f32_16x16x32_f16(A2[t][kk], B2[kk].h, C2[t], 0, 0, 0);

            // layer 3: dot(relu(h2), w3), reduce across quads
            float z = 0.0f;
#pragma unroll
            for (int t = 0; t < 4; ++t)
#pragma unroll
                for (int r = 0; r < 4; ++r)
                    z = fmaf(fmaxf(C2[t][r], 0.0f), w3v[t][r], z);
            z += __shfl_xor(z, 16);
            z += __shfl_xor(z, 32);
            // tanh(x) = 1 - 2/(exp(2x)+1); exp saturation -> exact +-1 tails
            const float e = __expf(2.0f * (z + bias3));
            o[u] = fmaf(-2.0f, __builtin_amdgcn_rcpf(e + 1.0f), 1.0f);
        }

        // ---- epilogue: NT/4 coalesced 256B stores ----
        // store s covers points tb*16 + 64*s + lane; value = o[4*s + quad]
#pragma unroll
        for (int s = 0; s < NT / 4; ++s) {
            const float osel = (quad == 0) ? o[4 * s + 0] : (quad == 1) ? o[4 * s + 1]
                             : (quad == 2) ? o[4 * s + 2] : o[4 * s + 3];
            const int pstore = tb * 16 + 64 * s + lane;
            if (pstore < nPoints) out[pstore] = osel;
        }
    }
}

extern "C" void kernel_launch(void* const* d_in, const int* in_sizes, int n_in,
                              void* d_out, int out_size, void* d_ws, size_t ws_size,
                              hipStream_t stream)
{
    const float* pts  = (const float*)d_in[0];
    const float* grid = (const float*)d_in[1];
    const float* W1   = (const float*)d_in[2];
    const float* b1   = (const float*)d_in[3];
    const float* W2   = (const float*)d_in[4];
    const float* b2   = (const float*)d_in[5];
    const float* W3   = (const float*)d_in[6];
    const float* b3   = (const float*)d_in[7];
    float* out = (float*)d_out;
    const int nPoints = in_sizes[0] / 3;

    // 2048 blocks x 4 waves = 8192 waves; 131072 tiles = 2 batches of 8/wave
    occ_mlp_kernel<<<dim3(2048), dim3(256), 0, stream>>>(
        pts, grid, W1, b1, W2, b2, W3, b3, out, nPoints);
}

// Round 6
// 258.257 us; speedup vs baseline: 1.0962x; 1.0962x over previous
//
#include <hip/hip_runtime.h>
#include <hip/hip_fp16.h>
#include <cstdint>
#include <cstddef>

// OccupancyModel: feats = grid[round(clip(p*127))]  (2M x 16 gather)
//   h1 = relu(feats @ W1^T + b1); h2 = relu(h1 @ W2^T + b2); occ = tanh(h2 @ W3^T + b3)
//
// R6: R5's LDS-DMA pipeline raced: ds_read of the staging buffer had NO wait
// on the global_load_lds DMA (vmcnt-tracked; compiler only inserts lgkmcnt
// waits for LDS reads -> stale data, absmax 0.33). This round makes every
// wait explicit and unambiguous:
//   * chunked double buffer (chunk = 4 tiles = 4KB; 2 bufs/wave; 32KB/block)
//   * iteration k: s_waitcnt vmcnt(0) drain (DMA(k) + pts(k+1) resident),
//     THEN DMA(k+1) -> other buffer (its reads finished in iter k-1, no WAR),
//     pts loads for k+2 into a 12-VGPR ring (cannot sink across the next
//     drain asm), THEN compute chunk k. DMA(k+1) flies across the whole
//     ~1200-cycle compute phase.
//   * register state stays tiny (ring only) -> no allocator war (R2-R4).
//
// MLP core verified R1-R4 (absmax 1.95e-3): fp16 MFMA 16x16x32,
// H^T = W @ feats^T, points on n-dim (col=lane&15); b1 folded into the
// layer-1 K-pad slot; layer1->2 relayout via 16 cross-quad bpermutes;
// tanh = 1 - 2/(exp(2x)+1).

typedef _Float16 half8 __attribute__((ext_vector_type(8)));
typedef float float4v __attribute__((ext_vector_type(4)));
typedef __attribute__((address_space(3))) uint32_t lds_u32;
typedef __attribute__((address_space(1))) const uint32_t glb_u32;

#define WPB 4   // waves per block
#define G   4   // tiles per chunk
#define NC  4   // chunks per wave  (wave covers G*NC*16 = 256 points)

__device__ inline uint32_t pack_f16x2(float a, float b) {
    union { _Float16 h[2]; uint32_t u; } v;
    v.h[0] = (_Float16)a;
    v.h[1] = (_Float16)b;
    return v.u;
}

__global__ __launch_bounds__(256, 3) void occ_mlp_kernel(
    const float* __restrict__ pts,
    const float* __restrict__ grid,
    const float* __restrict__ W1, const float* __restrict__ b1,
    const float* __restrict__ W2, const float* __restrict__ b2,
    const float* __restrict__ W3, const float* __restrict__ b3,
    float* __restrict__ out, int nPoints)
{
    // per-wave double buffer: G tiles x 16 pts x 16 f32 = 4KB each
    __shared__ float sbuf[WPB][2][G * 256];

    const int lane = threadIdx.x & 63;
    const int l15  = lane & 15;
    const int quad = lane >> 4;
    const int wib  = threadIdx.x >> 6;
    const int tile0 = (blockIdx.x * WPB + wib) * (G * NC);
    const int nTiles = (nPoints + 15) >> 4;
    if (tile0 >= nTiles) return;

    float* const buf0 = &sbuf[wib][0][0];
    float* const buf1 = &sbuf[wib][1][0];

    // ---- loop-invariant weight fragments ----
    // A layout: A[m = lane&15][k = quad*8 + j]. Layer1 K=16 padded to 32;
    // b1 folded at k=16 (quad2 j=0), bfrag's k=16 slot = 1.0.
    half8 A1[4];
#pragma unroll
    for (int t = 0; t < 4; ++t) {
        half8 f = {};
        if (quad < 2) {
            const float* row = W1 + (16 * t + l15) * 16 + quad * 8;
#pragma unroll
            for (int j = 0; j < 8; ++j) f[j] = (_Float16)row[j];
        } else if (quad == 2) {
            f[0] = (_Float16)b1[16 * t + l15];
        }
        A1[t] = f;
    }
    half8 A2[4][2];
#pragma unroll
    for (int t = 0; t < 4; ++t)
#pragma unroll
        for (int kk = 0; kk < 2; ++kk) {
            const float* row = W2 + (16 * t + l15) * 64 + 32 * kk + 8 * quad;
            half8 f;
#pragma unroll
            for (int j = 0; j < 8; ++j) f[j] = (_Float16)row[j];
            A2[t][kk] = f;
        }
    // C/D layout: col = lane&15 (point), row = quad*4 + reg.
    float4v bias2[4];
    float w3v[4][4];
#pragma unroll
    for (int t = 0; t < 4; ++t)
#pragma unroll
        for (int r = 0; r < 4; ++r) {
            int h = 16 * t + 4 * quad + r;
            bias2[t][r] = b2[h];
            w3v[t][r]   = W3[h];
        }
    const float bias3 = b3[0];

    // layer1->layer2 cross-quad shuffle plan
    const int src0 = l15 + 16 * ((2 * quad) & 3);
    const int src1 = l15 + 16 * ((2 * quad + 1) & 3);
    const bool sel = (quad >> 1) != 0;

    // ---- gather-lane mapping: lane = pt*4 + seg ----
    const int gpt  = lane >> 2;
    const int gseg = lane & 3;
    const int maxP = nPoints - 1;

    // pts ring: holds the NEXT chunk's points (12 VGPRs)
    float Rx[G], Ry[G], Rz[G];

    auto loadChunkPts = [&](int c) {
#pragma unroll
        for (int u = 0; u < G; ++u) {
            int p = (tile0 + c * G + u) * 16 + gpt;
            p = p > maxP ? maxP : p;
            const float* q = pts + 3 * p;
            Rx[u] = q[0]; Ry[u] = q[1]; Rz[u] = q[2];
        }
    };
    // DMA one chunk from the ring into buf: lane L -> LDS base + L*16B,
    // i.e. tile u, pt = L>>2, floats [L&3]*4..+3  == [pt][16 f32] row-major.
    auto dmaChunk = [&](float* buf) {
#pragma unroll
        for (int u = 0; u < G; ++u) {
            const int ix = (int)rintf(fminf(fmaxf(Rx[u] * 127.0f, 0.0f), 127.0f));
            const int iy = (int)rintf(fminf(fmaxf(Ry[u] * 127.0f, 0.0f), 127.0f));
            const int iz = (int)rintf(fminf(fmaxf(Rz[u] * 127.0f, 0.0f), 127.0f));
            const int ofs = ((((ix << 7) | iy) << 7) | iz) << 4;
            const float* ga = grid + ofs + (gseg << 2);
            __builtin_amdgcn_global_load_lds((glb_u32*)ga,
                                             (lds_u32*)(buf + u * 256), 16, 0, 0);
        }
    };

    // ---- prologue ----
    loadChunkPts(0);          // pts(0); toOfs below auto-waits (data dep)
    dmaChunk(buf0);           // DMA chunk 0
    loadChunkPts(1);          // pts(1) in flight

    // ---- chunk loop ----
#pragma unroll
    for (int k = 0; k < NC; ++k) {
        float* const bufC = (k & 1) ? buf1 : buf0;
        float* const bufN = (k & 1) ? buf0 : buf1;

        // Drain: DMA(k) landed, pts(k+1) resident. Also a compiler memory
        // fence: no load may move across it (keeps ring loads + DMA order).
        asm volatile("s_waitcnt vmcnt(0)" ::: "memory");

        if (k + 1 < NC) dmaChunk(bufN);      // uses ring = pts(k+1); WAR-safe
        if (k + 2 < NC) loadChunkPts(k + 2); // refill ring

        // ---- compute chunk k from bufC ----
        float o[G];
#pragma unroll
        for (int u = 0; u < G; ++u) {
            half8 bfrag = {};
            if (quad < 2) {
                const float4* gp = reinterpret_cast<const float4*>(
                    bufC + u * 256 + (l15 << 4) + (quad << 3));
                const float4 f0 = gp[0];
                const float4 f1 = gp[1];
                bfrag[0] = (_Float16)f0.x; bfrag[1] = (_Float16)f0.y;
                bfrag[2] = (_Float16)f0.z; bfrag[3] = (_Float16)f0.w;
                bfrag[4] = (_Float16)f1.x; bfrag[5] = (_Float16)f1.y;
                bfrag[6] = (_Float16)f1.z; bfrag[7] = (_Float16)f1.w;
            } else if (quad == 2) {
                bfrag[0] = (_Float16)1.0f;  // multiplies the folded b1 column
            }

            // layer 1 (bias via folded K-slot)
            float4v C1[4];
#pragma unroll
            for (int t = 0; t < 4; ++t) {
                float4v zacc = {};
                C1[t] = __builtin_amdgcn_mfma_f32_16x16x32_f16(A1[t], bfrag, zacc, 0, 0, 0);
            }

            // relu + fp16 pack
            uint32_t P[4][2];
#pragma unroll
            for (int t = 0; t < 4; ++t) {
                P[t][0] = pack_f16x2(fmaxf(C1[t][0], 0.0f), fmaxf(C1[t][1], 0.0f));
                P[t][1] = pack_f16x2(fmaxf(C1[t][2], 0.0f), fmaxf(C1[t][3], 0.0f));
            }

            // cross-quad shuffle into layer-2 B fragments
            union Frag { uint32_t u[4]; half8 h; } B2[2];
#pragma unroll
            for (int kk = 0; kk < 2; ++kk) {
                const uint32_t x0a = (uint32_t)__shfl((int)P[2 * kk    ][0], src0);
                const uint32_t x0b = (uint32_t)__shfl((int)P[2 * kk + 1][0], src0);
                const uint32_t x1a = (uint32_t)__shfl((int)P[2 * kk    ][1], src0);
                const uint32_t x1b = (uint32_t)__shfl((int)P[2 * kk + 1][1], src0);
                const uint32_t y0a = (uint32_t)__shfl((int)P[2 * kk    ][0], src1);
                const uint32_t y0b = (uint32_t)__shfl((int)P[2 * kk + 1][0], src1);
                const uint32_t y1a = (uint32_t)__shfl((int)P[2 * kk    ][1], src1);
                const uint32_t y1b = (uint32_t)__shfl((int)P[2 * kk + 1][1], src1);
                B2[kk].u[0] = sel ? x0b : x0a;
                B2[kk].u[1] = sel ? x1b : x1a;
                B2[kk].u[2] = sel ? y0b : y0a;
                B2[kk].u[3] = sel ? y1b : y1a;
            }

            // layer 2
            float4v C2[4];
#pragma unroll
            for (int t = 0; t < 4; ++t) C2[t] = bias2[t];
#pragma unroll
            for (int kk = 0; kk < 2; ++kk)
#pragma unroll
                for (int t = 0; t < 4; ++t)
                    C2[t] = __builtin_amdgcn_mfma_f32_16x16x32_f16(A2[t][kk], B2[kk].h, C2[t], 0, 0, 0);

            // layer 3: dot(relu(h2), w3), reduce across quads (broadcasts)
            float z = 0.0f;
#pragma unroll
            for (int t = 0; t < 4; ++t)
#pragma unroll
                for (int r = 0; r < 4; ++r)
                    z = fmaf(fmaxf(C2[t][r], 0.0f), w3v[t][r], z);
            z += __shfl_xor(z, 16);
            z += __shfl_xor(z, 32);
            const float e = __expf(2.0f * (z + bias3));
            o[u] = fmaf(-2.0f, __builtin_amdgcn_rcpf(e + 1.0f), 1.0f);
        }

        // chunk epilogue: one coalesced 256B store (G*16 = 64 points)
        const float osel = (quad == 0) ? o[0] : (quad == 1) ? o[1]
                         : (quad == 2) ? o[2] : o[3];
        const int pstore = (tile0 + k * G) * 16 + lane;
        if (pstore <= maxP) out[pstore] = osel;
    }
}

extern "C" void kernel_launch(void* const* d_in, const int* in_sizes, int n_in,
                              void* d_out, int out_size, void* d_ws, size_t ws_size,
                              hipStream_t stream)
{
    const float* pts  = (const float*)d_in[0];
    const float* grid = (const float*)d_in[1];
    const float* W1   = (const float*)d_in[2];
    const float* b1   = (const float*)d_in[3];
    const float* W2   = (const float*)d_in[4];
    const float* b2   = (const float*)d_in[5];
    const float* W3   = (const float*)d_in[6];
    const float* b3   = (const float*)d_in[7];
    float* out = (float*)d_out;
    const int nPoints = in_sizes[0] / 3;

    const int nTiles = (nPoints + 15) >> 4;
    const int tilesPerBlock = WPB * G * NC;          // 64
    const int nBlocks = (nTiles + tilesPerBlock - 1) / tilesPerBlock;  // 2048

    occ_mlp_kernel<<<dim3(nBlocks), dim3(256), 0, stream>>>(
        pts, grid, W1, b1, W2, b2, W3, b3, out, nPoints);
}